// Round 7
// baseline (118.290 us; speedup 1.0000x reference)
//
#include <hip/hip_runtime.h>
#include <math.h>

#define NT_ 365
#define NS_ 1024
#define NH_ 64
#define NG_ 32
#define NW_ 514        // NH*8 + 2
#define CH_ 64         // timesteps per chunk (= wave size)
#define NCHUNK_ 6      // ceil(365/64); tail steps are harmless dummies
#define WPB_ 8         // 8 waves/block, 128 blocks -> 2 waves/SIMD, zero LDS

__device__ __forceinline__ float sigmoidf(float v) {
  return 1.0f / (1.0f + expf(-v));
}

// lane j's value broadcast to all lanes (VALU pipe; j is compile-time)
__device__ __forceinline__ float blane(float v, int j) {
  return __int_as_float(__builtin_amdgcn_readlane(__float_as_int(v), j));
}

// ---- wave64 sum via DPP; total lands in lane 63 ----------------------------
template<int CTRL>
__device__ __forceinline__ float dpp_add(float x) {
  int t = __builtin_amdgcn_update_dpp(0, __float_as_int(x), CTRL, 0xf, 0xf, true);
  return x + __int_as_float(t);
}
__device__ __forceinline__ float wave_sum64(float x) {
  x = dpp_add<0x111>(x); // row_shr:1
  x = dpp_add<0x112>(x); // row_shr:2
  x = dpp_add<0x114>(x); // row_shr:4
  x = dpp_add<0x118>(x); // row_shr:8  -> lane15 of each row of 16
  x = dpp_add<0x142>(x); // row_bcast:15
  x = dpp_add<0x143>(x); // row_bcast:31 -> lane 63 = total
  return x;
}

// met = (Ps, Pl, relu(Ta), E); relu folded here since gm > 0
__device__ __forceinline__ float4 compute_met(float4 xv) {
  const float P = xv.x, E = xv.y, T1 = xv.z, T2 = xv.w;
  const float Ta = (T1 + T2) * 0.5f;
  float rP;
  if (T2 <= 0.0f) {
    rP = 0.0f;
  } else if (T1 >= 0.0f) {
    rP = 1.0f;
  } else {
    float r = (T1 + T2) / (T2 - T1);
    r = fminf(fmaxf(r, -0.999999f), 0.999999f);
    rP = 1.0f - acosf(r) * (1.0f / 3.1415f);
  }
  float4 m;
  m.x = (1.0f - rP) * P;   // Ps
  m.y = rP * P;            // Pl
  m.z = fmaxf(Ta, 0.0f);   // relu(Ta)
  m.w = E;
  return m;
}

// one wave per site; lane = hidden unit; met staged lane = timestep.
// 2 waves/SIMD for issue-rate (single-wave cap ~1 instr/4cyc), zero LDS in the
// steady loop so the per-CU DS pipe (R5's regression) carries no traffic.
__global__ __launch_bounds__(WPB_ * 64) void waternet_scan(
    const float* __restrict__ x,     // [NT, NS, 4]
    const float* __restrict__ xc,    // [NS, NG]
    const float* __restrict__ fc_w,  // [NW, NG]
    const float* __restrict__ fc_b,  // [NW]
    float* __restrict__ out)         // [NT, NS]
{
  const int tid  = threadIdx.x;
  const int lane = tid & 63;
  const int wv   = tid >> 6;
  const int site = (blockIdx.x << 3) + wv;
  const int us   = __builtin_amdgcn_readfirstlane(site);
  const float4* xp = (const float4*)x;

  // chunk-0 prefetch first: HBM latency hides under the gate GEMM
  float4 xcur = xp[lane * NS_ + site];  // t = lane

  // ---- prologue GEMM: w[site, j] = xc[site,:] . fc_w[j,:] + fc_b[j]
  float acc[8];
#pragma unroll
  for (int k = 0; k < 8; ++k) acc[k] = fc_b[k * NH_ + lane];
  float accq = fc_b[NW_ - 1];

  const float4* xcq = (const float4*)(xc + us * NG_);
  const float4* wq4 = (const float4*)fc_w;
#pragma unroll
  for (int g4 = 0; g4 < NG_ / 4; ++g4) {
    const float4 xv = xcq[g4];
#pragma unroll
    for (int k = 0; k < 8; ++k) {
      const float4 w = wq4[(k * NH_ + lane) * (NG_ / 4) + g4];
      acc[k] = fmaf(xv.x, w.x, acc[k]);
      acc[k] = fmaf(xv.y, w.y, acc[k]);
      acc[k] = fmaf(xv.z, w.z, acc[k]);
      acc[k] = fmaf(xv.w, w.w, acc[k]);
    }
    {
      const float4 w = wq4[(NW_ - 1) * (NG_ / 4) + g4];
      accq = fmaf(xv.x, w.x, accq);
      accq = fmaf(xv.y, w.y, accq);
      accq = fmaf(xv.z, w.z, accq);
      accq = fmaf(xv.w, w.w, accq);
    }
  }

  // ---- gates (per-lane = per hidden unit)
  const float gm = expf(acc[0]) + 1.0f;
  const float ge = sigmoidf(acc[1]) * 2.0f;
  const float go = sigmoidf(acc[2]);
  const float gl = expf(acc[3] * 2.0f);
  float mx = acc[4];
#pragma unroll
  for (int mm = 32; mm >= 1; mm >>= 1) mx = fmaxf(mx, __shfl_xor(mx, mm, 64));
  const float ex = expf(acc[4] - mx);
  float sm = ex;
#pragma unroll
  for (int mm = 32; mm >= 1; mm >>= 1) sm += __shfl_xor(sm, mm, 64);
  const float ga = ex / sm;
  const float gb = sigmoidf(acc[5]);
  const float kb = sigmoidf(acc[6]) * 0.1f;
  const float gi = sigmoidf(acc[7]);
  const float qb = fmaxf(accq, 0.0f) * (1.0f / NH_);
  const float kb1m = 1.0f - kb;                 // G0n = G*(1-kb)
  const float nge  = -ge;
  const float gq1  = go * (1.0f - gb) - 1.0f;   // y = ga*(H + M*gq1 + G*kb)

  // ---- scan state
  float S0 = 0.0f, H0 = 0.0f, G0 = 0.0f;
  float4 m = compute_met(xcur);                 // current chunk met, lane = t

  for (int c = 0; c < NCHUNK_; ++c) {
    // prefetch chunk c+1 (clamped dummy for the tail) — in flight all chunk
    int tn = (c + 1) * CH_ + lane;
    tn = (tn < NT_) ? tn : (NT_ - 1);
    const float4 xnext = xp[tn * NS_ + site];

    float ycol = 0.0f;  // lane j ends up holding Y for timestep c*64+j
#pragma unroll
    for (int j = 0; j < CH_; ++j) {
      // broadcast step-j met from lane j (compile-time lane index)
      const float Ps = blane(m.x, j);
      const float Pl = blane(m.y, j);
      const float Tr = blane(m.z, j);
      const float E  = blane(m.w, j);

      const float melt = Tr * gm;
      const float Sm   = fminf(S0, melt);
      const float base = H0 + Sm;
      S0 = (S0 - Sm) + Ps;
      const float t3 = fmaf(Pl, gi, base);
      const float H  = fmaxf(fmaf(E, nge, t3), 0.0f);
      const float M  = fminf(H, gl);
      const float Q2a = M * go;
      H0 = fminf(H - Q2a, gl);
      const float G = fmaf(Q2a, gb, G0);
      G0 = G * kb1m;
      const float y = fmaf(G, kb, fmaf(M, gq1, H)) * ga;  // ga*(Q1+Q2+Q3)

      // wave sum (off the recurrence critical path) -> bank into lane j:
      // readlane(.,63) gives an SGPR; cndmask deposits it into lane j only.
      const float tot = wave_sum64(y);
      const float ts  = __int_as_float(
          __builtin_amdgcn_readlane(__float_as_int(tot), 63));
      ycol = (lane == j) ? ts : ycol;   // v_cmp + v_cndmask, VALU pipe
    }

    // store chunk outputs: lane j -> out[(c*64+j)*NS + site]
    const int t_out = c * CH_ + lane;
    if (t_out < NT_) out[t_out * NS_ + site] = ycol + qb;

    if (c + 1 < NCHUNK_) m = compute_met(xnext);  // next chunk met (pure VALU)
  }
}

extern "C" void kernel_launch(void* const* d_in, const int* in_sizes, int n_in,
                              void* d_out, int out_size, void* d_ws, size_t ws_size,
                              hipStream_t stream) {
  const float* x    = (const float*)d_in[0];
  const float* xc   = (const float*)d_in[1];
  const float* fc_w = (const float*)d_in[2];
  const float* fc_b = (const float*)d_in[3];
  float* out = (float*)d_out;

  // 1024 sites / 8 waves per block = 128 blocks -> one per CU, 2 waves/SIMD
  hipLaunchKernelGGL(waternet_scan, dim3(NS_ / WPB_), dim3(WPB_ * 64), 0, stream,
                     x, xc, fc_w, fc_b, out);
}

// Round 8
// 95.942 us; speedup vs baseline: 1.2329x; 1.2329x over previous
//
#include <hip/hip_runtime.h>
#include <math.h>

#define NT_ 365
#define NS_ 1024
#define NH_ 64
#define NG_ 32
#define NW_ 514        // NH*8 + 2
#define CH_ 64         // timesteps per chunk (= wave size)
#define NCHUNK_ 6      // ceil(365/64); tail steps are harmless dummies
#define YSTR_ 130      // y-row stride in floats: 128 data + 2 pad (8B aligned)

typedef float v2 __attribute__((ext_vector_type(2)));   // -> v_pk_*_f32

__device__ __forceinline__ float sigmoidf(float v) {
  return 1.0f / (1.0f + expf(-v));
}

__device__ __forceinline__ v2 pk_fma(v2 a, v2 b, v2 c) {
  return __builtin_elementwise_fma(a, b, c);
}
__device__ __forceinline__ v2 pk_min(v2 a, v2 b) {
  return __builtin_elementwise_min(a, b);
}
__device__ __forceinline__ v2 pk_max(v2 a, v2 b) {
  return __builtin_elementwise_max(a, b);
}

// met = (Ps, Pl, relu(Ta), E); relu folded here since gm > 0
__device__ __forceinline__ float4 compute_met(float4 xv) {
  const float P = xv.x, E = xv.y, T1 = xv.z, T2 = xv.w;
  const float Ta = (T1 + T2) * 0.5f;
  float rP;
  if (T2 <= 0.0f) {
    rP = 0.0f;
  } else if (T1 >= 0.0f) {
    rP = 1.0f;
  } else {
    float r = (T1 + T2) / (T2 - T1);
    r = fminf(fmaxf(r, -0.999999f), 0.999999f);
    rP = 1.0f - acosf(r) * (1.0f / 3.1415f);
  }
  float4 m;
  m.x = (1.0f - rP) * P;   // Ps
  m.y = rP * P;            // Pl
  m.z = fmaxf(Ta, 0.0f);   // relu(Ta)
  m.w = E;
  return m;
}

// One wave = TWO adjacent sites (packed fp32, lane = hidden unit).
// 256 blocks x 128 thr -> 1 block/CU, 2 waves/CU: balances per-wave issue
// (~20 instr/step for 2 sites) against the per-CU DS pipe (R5's limiter).
// Cross-lane ops avoided entirely (R7's regression): met broadcasts and the
// Y-reduction go through per-wave LDS slices with immediate offsets.
__global__ __launch_bounds__(128) void waternet_scan(
    const float* __restrict__ x,     // [NT, NS, 4]
    const float* __restrict__ xc,    // [NS, NG]
    const float* __restrict__ fc_w,  // [NW, NG]
    const float* __restrict__ fc_b,  // [NW]
    float* __restrict__ out)         // [NT, NS]
{
  __shared__ float4 smet[2][2][CH_];     // [wave][half][step] met pairs, 4 KB
  __shared__ float  ytile[2][CH_ * YSTR_]; // [wave][step*130+2h], 66.6 KB

  const int tid  = threadIdx.x;
  const int lane = tid & 63;
  const int wv   = tid >> 6;
  const int sA   = (blockIdx.x << 2) + (wv << 1);  // even site of the pair
  const int usA  = __builtin_amdgcn_readfirstlane(sA);
  const float4* xp = (const float4*)x;

  // chunk-0 prefetch first (t = lane): HBM latency hides under the gate GEMM
  float4 xcA = xp[lane * NS_ + sA];
  float4 xcB = xp[lane * NS_ + sA + 1];

  // ---- prologue GEMM for BOTH sites: w[s, j] = xc[s,:] . fc_w[j,:] + fc_b[j]
  v2 acc[8];
#pragma unroll
  for (int k = 0; k < 8; ++k) acc[k] = (v2)(fc_b[k * NH_ + lane]);
  v2 accq = (v2)(fc_b[NW_ - 1]);

  const float4* xcqA = (const float4*)(xc + usA * NG_);
  const float4* xcqB = (const float4*)(xc + (usA + 1) * NG_);
  const float4* wq4  = (const float4*)fc_w;
#pragma unroll
  for (int g4 = 0; g4 < NG_ / 4; ++g4) {
    const float4 xa = xcqA[g4];
    const float4 xb = xcqB[g4];
    const v2 x0 = {xa.x, xb.x}, x1 = {xa.y, xb.y};
    const v2 x2 = {xa.z, xb.z}, x3 = {xa.w, xb.w};
#pragma unroll
    for (int k = 0; k < 8; ++k) {
      const float4 w = wq4[(k * NH_ + lane) * (NG_ / 4) + g4];
      acc[k] = pk_fma(x0, (v2)(w.x), acc[k]);
      acc[k] = pk_fma(x1, (v2)(w.y), acc[k]);
      acc[k] = pk_fma(x2, (v2)(w.z), acc[k]);
      acc[k] = pk_fma(x3, (v2)(w.w), acc[k]);
    }
    {
      const float4 w = wq4[(NW_ - 1) * (NG_ / 4) + g4];
      accq = pk_fma(x0, (v2)(w.x), accq);
      accq = pk_fma(x1, (v2)(w.y), accq);
      accq = pk_fma(x2, (v2)(w.z), accq);
      accq = pk_fma(x3, (v2)(w.w), accq);
    }
  }

  // ---- gates, packed per lane (component = site)
  v2 gm, ge, go, gl, ga, gb, kb, gi;
  {
    gm = v2{expf(acc[0].x), expf(acc[0].y)} + (v2)(1.0f);
    ge = v2{sigmoidf(acc[1].x), sigmoidf(acc[1].y)} * (v2)(2.0f);
    go = v2{sigmoidf(acc[2].x), sigmoidf(acc[2].y)};
    gl = v2{expf(acc[3].x * 2.0f), expf(acc[3].y * 2.0f)};
    // softmax over the 64 lanes, per component
    float mxa = acc[4].x, mxb = acc[4].y;
#pragma unroll
    for (int mm = 32; mm >= 1; mm >>= 1) {
      mxa = fmaxf(mxa, __shfl_xor(mxa, mm, 64));
      mxb = fmaxf(mxb, __shfl_xor(mxb, mm, 64));
    }
    const float exa = expf(acc[4].x - mxa), exb = expf(acc[4].y - mxb);
    float sma = exa, smb = exb;
#pragma unroll
    for (int mm = 32; mm >= 1; mm >>= 1) {
      sma += __shfl_xor(sma, mm, 64);
      smb += __shfl_xor(smb, mm, 64);
    }
    ga = v2{exa / sma, exb / smb};
    gb = v2{sigmoidf(acc[5].x), sigmoidf(acc[5].y)};
    kb = v2{sigmoidf(acc[6].x), sigmoidf(acc[6].y)} * (v2)(0.1f);
    gi = v2{sigmoidf(acc[7].x), sigmoidf(acc[7].y)};
  }
  const v2 qb   = pk_max(accq, (v2)(0.0f)) * (v2)(1.0f / NH_);
  const v2 kb1m = (v2)(1.0f) - kb;                    // G0' = G*(1-kb)
  const v2 nge  = -ge;
  const v2 gq1  = go * ((v2)(1.0f) - gb) - (v2)(1.0f); // y = ga*(H+M*gq1+G*kb)
  const v2 zero = (v2)(0.0f);

  // ---- scan state (packed: 2 sites)
  v2 S0 = zero, H0 = zero, G0 = zero;

  // stage chunk-0 met: lane j -> step j, both sites, interleaved pair layout
  {
    const float4 mA = compute_met(xcA);
    const float4 mB = compute_met(xcB);
    smet[wv][0][lane] = make_float4(mA.x, mB.x, mA.y, mB.y); // PsA PsB PlA PlB
    smet[wv][1][lane] = make_float4(mA.z, mB.z, mA.w, mB.w); // TrA TrB EA  EB
  }

  float* yrow = &ytile[wv][2 * lane];          // step j writes yrow[j*YSTR_]
  const float* yred = &ytile[wv][lane * YSTR_]; // reduce: lane sums its row

  for (int c = 0; c < NCHUNK_; ++c) {
    // prefetch chunk c+1 (clamped dummy tail) — in flight across the chunk
    int tn = (c + 1) * CH_ + lane;
    tn = (tn < NT_) ? tn : (NT_ - 1);
    const float4 xnA = xp[tn * NS_ + sA];
    const float4 xnB = xp[tn * NS_ + sA + 1];

    const float4* mp0 = &smet[wv][0][0];
    const float4* mp1 = &smet[wv][1][0];
#pragma unroll
    for (int j = 0; j < CH_; ++j) {
      const float4 a = mp0[j];                 // ds_read_b128, uniform bcast
      const float4 b = mp1[j];
      const v2 Ps = {a.x, a.y}, Pl = {a.z, a.w};
      const v2 Tr = {b.x, b.y}, E  = {b.z, b.w};

      const v2 melt = Tr * gm;
      const v2 Sm   = pk_min(S0, melt);
      const v2 base = H0 + Sm;
      S0 = (S0 - Sm) + Ps;
      const v2 t3  = pk_fma(Pl, gi, base);
      const v2 H   = pk_max(pk_fma(E, nge, t3), zero);
      const v2 M   = pk_min(H, gl);
      const v2 Q2a = M * go;
      H0 = pk_min(H - Q2a, gl);
      const v2 G = pk_fma(Q2a, gb, G0);
      G0 = G * kb1m;
      const v2 y = pk_fma(G, kb, pk_fma(M, gq1, H)) * ga;
      *(v2*)&yrow[j * YSTR_] = y;              // ds_write_b64
    }

    // transposed reduction: lane t' sums its 128-float row (b64 pairs)
    v2 r0 = zero, r1 = zero;
#pragma unroll
    for (int h = 0; h < CH_; h += 2) {
      r0 += *(const v2*)&yred[2 * h];
      r1 += *(const v2*)&yred[2 * h + 2];
    }
    const v2 tot = (r0 + r1) + qb;
    const int t_out = c * CH_ + lane;
    if (t_out < NT_) *(v2*)(out + t_out * NS_ + sA) = tot;  // dwordx2, aligned

    if (c + 1 < NCHUNK_) {                     // stage next chunk's met
      const float4 mA = compute_met(xnA);
      const float4 mB = compute_met(xnB);
      smet[wv][0][lane] = make_float4(mA.x, mB.x, mA.y, mB.y);
      smet[wv][1][lane] = make_float4(mA.z, mB.z, mA.w, mB.w);
    }
  }
}

extern "C" void kernel_launch(void* const* d_in, const int* in_sizes, int n_in,
                              void* d_out, int out_size, void* d_ws, size_t ws_size,
                              hipStream_t stream) {
  const float* x    = (const float*)d_in[0];
  const float* xc   = (const float*)d_in[1];
  const float* fc_w = (const float*)d_in[2];
  const float* fc_b = (const float*)d_in[3];
  float* out = (float*)d_out;

  // 512 site-pairs -> 256 blocks x 2 waves (128 thr): 1 block/CU, 2 waves/CU
  hipLaunchKernelGGL(waternet_scan, dim3(NS_ / 4), dim3(128), 0, stream,
                     x, xc, fc_w, fc_b, out);
}

// Round 9
// 88.318 us; speedup vs baseline: 1.3394x; 1.0863x over previous
//
#include <hip/hip_runtime.h>
#include <math.h>

#define NT_ 365
#define NS_ 1024
#define NH_ 64
#define NG_ 32
#define NW_ 514        // NH*8 + 2
#define CH_ 64         // timesteps per chunk (= wave size)
#define NCHUNK_ 6      // ceil(365/64); tail steps are harmless dummies
#define YPAD_ 65       // padded row stride: bank = (lane+j)%32, conflict-free R/W
#define SUB_ 8         // met sub-chunk: register double-buffer depth

__device__ __forceinline__ float sigmoidf(float v) {
  return 1.0f / (1.0f + expf(-v));
}

// met = (Ps, Pl, relu(Ta), E); relu folded here since gm > 0
__device__ __forceinline__ float4 compute_met(float4 xv) {
  const float P = xv.x, E = xv.y, T1 = xv.z, T2 = xv.w;
  const float Ta = (T1 + T2) * 0.5f;
  float rP;
  if (T2 <= 0.0f) {
    rP = 0.0f;
  } else if (T1 >= 0.0f) {
    rP = 1.0f;
  } else {
    float r = (T1 + T2) / (T2 - T1);
    r = fminf(fmaxf(r, -0.999999f), 0.999999f);
    rP = 1.0f - acosf(r) * (1.0f / 3.1415f);
  }
  float4 m;
  m.x = (1.0f - rP) * P;   // Ps
  m.y = rP * P;            // Pl
  m.z = fmaxf(Ta, 0.0f);   // relu(Ta)
  m.w = E;
  return m;
}

// One wave per site (1024 waves -> 1 wave/SIMD on the whole machine), lane =
// hidden unit. Met is staged to LDS once per 64-step chunk (lane = step), then
// consumed through an 8-step REGISTER double-buffer so the ~120-cyc ds_read
// latency (the R4 fixed stall suspect) overlaps the previous sub-chunk's
// compute. Y goes to a padded LDS tile; one transposed reduce per chunk.
// Outer chunk loop forced rolled to keep the body I-cache resident.
__global__ __launch_bounds__(256) void waternet_scan(
    const float* __restrict__ x,     // [NT, NS, 4]
    const float* __restrict__ xc,    // [NS, NG]
    const float* __restrict__ fc_w,  // [NW, NG]
    const float* __restrict__ fc_b,  // [NW]
    float* __restrict__ out)         // [NT, NS]
{
  __shared__ float4 smet[4][CH_];          // 4 KB:  [wave][step] met
  __shared__ float  ytile[4][CH_ * YPAD_]; // 66.6 KB: per-wave y rows

  const int tid  = threadIdx.x;
  const int lane = tid & 63;
  const int wv   = tid >> 6;
  const int site = (blockIdx.x << 2) + wv;
  const int us   = __builtin_amdgcn_readfirstlane(site);
  const float4* xp = (const float4*)x;

  // chunk-0 prefetch first: HBM latency hides under the gate GEMM
  float4 xcur = xp[lane * NS_ + site];  // t = lane

  // ---- prologue GEMM: w[site, j] = xc[site,:] . fc_w[j,:] + fc_b[j]
  float acc[8];
#pragma unroll
  for (int k = 0; k < 8; ++k) acc[k] = fc_b[k * NH_ + lane];
  float accq = fc_b[NW_ - 1];

  const float4* xcq = (const float4*)(xc + us * NG_);
  const float4* wq4 = (const float4*)fc_w;
#pragma unroll
  for (int g4 = 0; g4 < NG_ / 4; ++g4) {
    const float4 xv = xcq[g4];
#pragma unroll
    for (int k = 0; k < 8; ++k) {
      const float4 w = wq4[(k * NH_ + lane) * (NG_ / 4) + g4];
      acc[k] = fmaf(xv.x, w.x, acc[k]);
      acc[k] = fmaf(xv.y, w.y, acc[k]);
      acc[k] = fmaf(xv.z, w.z, acc[k]);
      acc[k] = fmaf(xv.w, w.w, acc[k]);
    }
    {
      const float4 w = wq4[(NW_ - 1) * (NG_ / 4) + g4];
      accq = fmaf(xv.x, w.x, accq);
      accq = fmaf(xv.y, w.y, accq);
      accq = fmaf(xv.z, w.z, accq);
      accq = fmaf(xv.w, w.w, accq);
    }
  }

  // ---- gates (per-lane = per hidden unit)
  const float gm = expf(acc[0]) + 1.0f;
  const float ge = sigmoidf(acc[1]) * 2.0f;
  const float go = sigmoidf(acc[2]);
  const float gl = expf(acc[3] * 2.0f);
  float mx = acc[4];
#pragma unroll
  for (int mm = 32; mm >= 1; mm >>= 1) mx = fmaxf(mx, __shfl_xor(mx, mm, 64));
  const float ex = expf(acc[4] - mx);
  float sm = ex;
#pragma unroll
  for (int mm = 32; mm >= 1; mm >>= 1) sm += __shfl_xor(sm, mm, 64);
  const float ga = ex / sm;
  const float gb = sigmoidf(acc[5]);
  const float kb = sigmoidf(acc[6]) * 0.1f;
  const float gi = sigmoidf(acc[7]);
  const float qb = fmaxf(accq, 0.0f) * (1.0f / NH_);
  const float kb1m = 1.0f - kb;                 // G0' = G*(1-kb)
  const float nge  = -ge;
  const float gq1  = go * (1.0f - gb) - 1.0f;   // y = ga*(H + M*gq1 + G*kb)

  // ---- scan state
  float S0 = 0.0f, H0 = 0.0f, G0 = 0.0f;

  // stage chunk-0 met (lane = step); per-wave slice + in-order DS -> no barrier
  smet[wv][lane] = compute_met(xcur);

  auto step = [&](const float4 mt, float* ywaddr) {
    const float melt = mt.z * gm;                   // relu(Ta)*gm
    const float Sm   = fminf(S0, melt);
    const float base = H0 + Sm;
    S0 = (S0 - Sm) + mt.x;
    const float t3 = fmaf(mt.y, gi, base);
    const float H  = fmaxf(fmaf(mt.w, nge, t3), 0.0f);
    const float M  = fminf(H, gl);
    const float Q2a = M * go;
    H0 = fminf(H - Q2a, gl);
    const float G = fmaf(Q2a, gb, G0);
    G0 = G * kb1m;
    *ywaddr = fmaf(G, kb, fmaf(M, gq1, H)) * ga;    // ga*(Q1+Q2+Q3)
  };

  float*       yw = &ytile[wv][lane];          // step j writes yw[j*YPAD_]
  const float* yr = &ytile[wv][lane * YPAD_];  // reduce: lane sums its row

#pragma unroll 1   // keep body ~13 KB: I-cache resident across 6 iterations
  for (int c = 0; c < NCHUNK_; ++c) {
    // prefetch chunk c+1 from HBM (clamped dummy tail) — in flight all chunk
    int tn = (c + 1) * CH_ + lane;
    tn = (tn < NT_) ? tn : (NT_ - 1);
    const float4 xnext = xp[tn * NS_ + site];

    const float4* mp = &smet[wv][0];

    // ---- 8-step register double-buffer: loads for sub-chunk k+1 issue
    // before sub-chunk k's compute -> ds_read latency fully covered.
    float4 mb0[SUB_], mb1[SUB_];
#pragma unroll
    for (int u = 0; u < SUB_; ++u) mb0[u] = mp[u];

#pragma unroll
    for (int sc = 0; sc < CH_ / SUB_; ++sc) {
      float4*       cur = (sc & 1) ? mb1 : mb0;
      float4*       nxt = (sc & 1) ? mb0 : mb1;
      if (sc < CH_ / SUB_ - 1) {
#pragma unroll
        for (int u = 0; u < SUB_; ++u) nxt[u] = mp[SUB_ * (sc + 1) + u];
      }
#pragma unroll
      for (int u = 0; u < SUB_; ++u)
        step(cur[u], yw + (SUB_ * sc + u) * YPAD_);
    }

    // ---- transposed reduction: lane t' sums row t' (bank=(t'+h)%32, free)
    float r0 = 0.0f, r1 = 0.0f, r2 = 0.0f, r3 = 0.0f;
#pragma unroll
    for (int h = 0; h < CH_; h += 4) {
      r0 += yr[h + 0];
      r1 += yr[h + 1];
      r2 += yr[h + 2];
      r3 += yr[h + 3];
    }
    const int t_out = c * CH_ + lane;
    if (t_out < NT_) out[t_out * NS_ + site] = ((r0 + r1) + (r2 + r3)) + qb;

    // stage next chunk's met (reads above already issued -> in-order safe)
    if (c + 1 < NCHUNK_) smet[wv][lane] = compute_met(xnext);
  }
}

extern "C" void kernel_launch(void* const* d_in, const int* in_sizes, int n_in,
                              void* d_out, int out_size, void* d_ws, size_t ws_size,
                              hipStream_t stream) {
  const float* x    = (const float*)d_in[0];
  const float* xc   = (const float*)d_in[1];
  const float* fc_w = (const float*)d_in[2];
  const float* fc_b = (const float*)d_in[3];
  float* out = (float*)d_out;

  // 1024 sites, one wave each; 4 waves/block -> 256 blocks, 1 wave/SIMD
  // across the full machine (sites == SIMDs, so this is the max spread).
  hipLaunchKernelGGL(waternet_scan, dim3(NS_ / 4), dim3(256), 0, stream,
                     x, xc, fc_w, fc_b, out);
}